// Round 10
// baseline (542.703 us; speedup 1.0000x reference)
//
#include <hip/hip_runtime.h>
#include <hip/hip_bf16.h>

#define NN 50000
#define NE 800000

typedef __bf16 bf16x8 __attribute__((ext_vector_type(8)));
typedef float f32x4 __attribute__((ext_vector_type(4)));

__device__ __forceinline__ unsigned short f2bu(float f) {
    return __builtin_bit_cast(unsigned short, (__bf16)f);
}
__device__ __forceinline__ float b2f(unsigned short u) {
    return (float)__builtin_bit_cast(__bf16, u);
}

// ---------------------------------------------------------------------------
// f32 -> bf16 convert (x -> xb), 8 elements per thread
// ---------------------------------------------------------------------------
__global__ void k_cvt(const float* __restrict__ x, unsigned short* __restrict__ xb, int n8) {
    int i = blockIdx.x * blockDim.x + threadIdx.x;
    if (i >= n8) return;
    float4 a = ((const float4*)x)[i * 2];
    float4 b = ((const float4*)x)[i * 2 + 1];
    bf16x8 v;
    v[0] = (__bf16)a.x; v[1] = (__bf16)a.y; v[2] = (__bf16)a.z; v[3] = (__bf16)a.w;
    v[4] = (__bf16)b.x; v[5] = (__bf16)b.y; v[6] = (__bf16)b.z; v[7] = (__bf16)b.w;
    ((uint4*)xb)[i] = __builtin_bit_cast(uint4, v);
}

// ---------------------------------------------------------------------------
// in-degree histogram over dst = ei[E..2E)
// ---------------------------------------------------------------------------
__global__ void k_deg(const int* __restrict__ ei, int* __restrict__ deg, int E) {
    int e = blockIdx.x * blockDim.x + threadIdx.x;
    if (e < E) atomicAdd(&deg[ei[E + e]], 1);
}

// ---------------------------------------------------------------------------
// Hierarchical exclusive scan of deg[0..n) -> cursor, 256 blocks.
// ---------------------------------------------------------------------------
__global__ __launch_bounds__(256)
void k_scan1(const int* __restrict__ deg, int* __restrict__ part, int n) {
    const int b = blockIdx.x, t = threadIdx.x;
    const int chunk = (n + gridDim.x - 1) / gridDim.x;
    const int lo = b * chunk;
    const int cnt = min(chunk, n - lo);
    int v = (t < cnt) ? deg[lo + t] : 0;
    v += __shfl_xor(v, 1); v += __shfl_xor(v, 2); v += __shfl_xor(v, 4);
    v += __shfl_xor(v, 8); v += __shfl_xor(v, 16); v += __shfl_xor(v, 32);
    __shared__ int red[4];
    if ((t & 63) == 0) red[t >> 6] = v;
    __syncthreads();
    if (t == 0) part[b] = red[0] + red[1] + red[2] + red[3];
}

__global__ __launch_bounds__(256)
void k_scan2(int* __restrict__ part) {
    __shared__ int tmp[256];
    const int t = threadIdx.x;
    const int v = part[t];
    tmp[t] = v;
    __syncthreads();
    int val = v;
    for (int off = 1; off < 256; off <<= 1) {
        int y = (t >= off) ? tmp[t - off] : 0;
        __syncthreads();
        val += y;
        tmp[t] = val;
        __syncthreads();
    }
    part[t] = val - v;   // exclusive
}

__global__ __launch_bounds__(256)
void k_scan3(const int* __restrict__ deg, const int* __restrict__ part,
             int* __restrict__ cursor, int n) {
    __shared__ int tmp[256];
    const int b = blockIdx.x, t = threadIdx.x;
    const int chunk = (n + gridDim.x - 1) / gridDim.x;
    const int lo = b * chunk;
    const int cnt = min(chunk, n - lo);
    const int v = (t < cnt) ? deg[lo + t] : 0;
    tmp[t] = v;
    __syncthreads();
    int val = v;
    for (int off = 1; off < 256; off <<= 1) {
        int y = (t >= off) ? tmp[t - off] : 0;
        __syncthreads();
        val += y;
        tmp[t] = val;
        __syncthreads();
    }
    if (t < cnt) cursor[lo + t] = part[b] + val - v;   // exclusive + block offset
}

// ---------------------------------------------------------------------------
// scatter edges into dst-sorted order using cursor (post: cursor[n]=segment end)
// ---------------------------------------------------------------------------
__global__ void k_scatter(const int* __restrict__ ei, const float* __restrict__ ew,
                          int* __restrict__ cursor, int* __restrict__ srcS,
                          float2* __restrict__ ewS, int E) {
    int e = blockIdx.x * blockDim.x + threadIdx.x;
    if (e >= E) return;
    int d = ei[E + e];
    int s = atomicAdd(&cursor[d], 1);
    srcS[s] = ei[e];
    ewS[s] = ((const float2*)ew)[e];
}

// ---------------------------------------------------------------------------
// Dense MFMA GEMM, bf16 input rows, W/bias f32 -> registers.
// Tile 128 x NOUT, 4 waves (2x2), A fragment-major in LDS (520-pad + swizzle).
// MOUT: 0 = plain bf16 store; 1 = relu->bf16; 2 = relu->mu f32 + z bf16 /
//       logvar f32; 3 = tanh->f32
// ---------------------------------------------------------------------------
template<int KP, int NOUT, int MOUT>
__global__ __launch_bounds__(256, 2)
void k_dense(const unsigned short* __restrict__ Xb, const float* __restrict__ W,
             const float* __restrict__ bias, float* __restrict__ o0,
             float* __restrict__ o1, unsigned short* __restrict__ bo, int M)
{
    constexpr int BLOCK_M = 128;
    constexpr int CH = KP / 8;
    constexpr int KSTEPS = KP / 32;
    constexpr int FM = 4;
    constexpr int FN = NOUT / 32;
    constexpr int BLK = 520;

    __shared__ unsigned short Alds[8 * KSTEPS * BLK];

    const int tid = threadIdx.x;
    const int lane = tid & 63;
    const int w = tid >> 6;
    const int lrow = lane & 15;
    const int lkg = lane >> 4;
    const int wrow0 = (w >> 1) * 64;
    const int cb0 = (w & 1) * (NOUT / 2);

    bf16x8 bfr[KSTEPS][FN];
    float eb[FN];
#pragma unroll
    for (int nf = 0; nf < FN; ++nf) {
        int col = cb0 + nf * 16 + lrow;
#pragma unroll
        for (int ks = 0; ks < KSTEPS; ++ks)
#pragma unroll
            for (int j = 0; j < 8; ++j) {
                int k = ks * 32 + lkg * 8 + j;
                bfr[ks][nf][j] = (__bf16)W[k * NOUT + col];
            }
        if constexpr (MOUT != 0) eb[nf] = bias[col];
        else eb[nf] = 0.f;
    }

    const int ntiles = (M + BLOCK_M - 1) / BLOCK_M;
    for (int tile = blockIdx.x; tile < ntiles; tile += gridDim.x) {
        const int base = tile * BLOCK_M;
        __syncthreads();
        for (int t = tid; t < BLOCK_M * CH; t += 256) {
            int row = t / CH;
            int c = t % CH;
            int r = base + row;
            uint4 val = make_uint4(0, 0, 0, 0);
            if (r < M) val = *((const uint4*)(Xb + (size_t)r * KP) + c);
            int mb = row >> 4, lr = row & 15, ks = c >> 2, q = c & 3;
            int unit = (q * 16 + lr) ^ (q << 1);
            *(uint4*)&Alds[(mb * KSTEPS + ks) * BLK + unit * 8] = val;
        }
        __syncthreads();

        f32x4 acc[FM][FN];
#pragma unroll
        for (int mf = 0; mf < FM; ++mf)
#pragma unroll
            for (int nf = 0; nf < FN; ++nf)
                acc[mf][nf] = 0;

        const int runit = lane ^ (lkg << 1);
#pragma unroll
        for (int ks = 0; ks < KSTEPS; ++ks) {
            bf16x8 afr[FM];
#pragma unroll
            for (int mf = 0; mf < FM; ++mf) {
                int mb = (wrow0 >> 4) + mf;
                afr[mf] = *(const bf16x8*)&Alds[(mb * KSTEPS + ks) * BLK + runit * 8];
            }
#pragma unroll
            for (int mf = 0; mf < FM; ++mf)
#pragma unroll
                for (int nf = 0; nf < FN; ++nf)
                    acc[mf][nf] = __builtin_amdgcn_mfma_f32_16x16x32_bf16(
                        afr[mf], bfr[ks][nf], acc[mf][nf], 0, 0, 0);
        }

#pragma unroll
        for (int mf = 0; mf < FM; ++mf) {
#pragma unroll
            for (int reg = 0; reg < 4; ++reg) {
                int row = wrow0 + mf * 16 + lkg * 4 + reg;
                int r = base + row;
                if (r < M) {
#pragma unroll
                    for (int nf = 0; nf < FN; ++nf) {
                        int col = cb0 + nf * 16 + lrow;
                        float tv = acc[mf][nf][reg] + eb[nf];
                        if constexpr (MOUT == 0) {
                            bo[(size_t)r * NOUT + col] = f2bu(tv);
                        } else if constexpr (MOUT == 1) {
                            bo[(size_t)r * NOUT + col] = f2bu(fmaxf(tv, 0.f));
                        } else if constexpr (MOUT == 2) {
                            float v = fmaxf(tv, 0.f);
                            if (col < 64) {
                                o0[(size_t)r * 64 + col] = v;        // mu
                                bo[(size_t)r * 64 + col] = f2bu(v);  // z
                            } else {
                                o1[(size_t)r * 64 + (col - 64)] = v; // logvar
                            }
                        } else {
                            o0[(size_t)r * NOUT + col] = tanhf(tv);
                        }
                    }
                }
            }
        }
    }
}

// ---------------------------------------------------------------------------
// Per-node segment gather-reduce (NO atomics), 16-deep batching with
// sched_barrier(0) pinning so hipcc cannot sink the gathers to their uses
// (R9: compiler serialized the batch, VGPR=24 tell). Phases per 16-edge chunk:
//   P1: 16 srcS + 16 ewS loads  | sched_barrier
//   P2: 16 Y-row gathers        | sched_barrier
//   P3: compute
// ---------------------------------------------------------------------------
template<int NOUT>
__global__ __launch_bounds__(256)
void k_agg(const unsigned short* __restrict__ Yb, const int* __restrict__ srcS,
           const float2* __restrict__ ewS, const float* __restrict__ er,
           const float* __restrict__ bc, const int* __restrict__ cursor,
           const int* __restrict__ deg, unsigned short* __restrict__ meanb, int NV)
{
    constexpr int VC = NOUT / 64;
    constexpr int UF = 16;
    const int lane = threadIdx.x & 63;
    const int team = threadIdx.x >> 6;
    const int n = blockIdx.x * 4 + team;
    if (n >= NV) return;
    const int c0 = lane * VC;

    float e0[VC], e1[VC], bcv[VC], acc[VC];
#pragma unroll
    for (int v = 0; v < VC; ++v) {
        e0[v] = er[c0 + v];
        e1[v] = er[NOUT + c0 + v];
        bcv[v] = bc[c0 + v];
        acc[v] = 0.f;
    }

    const int len = deg[n];
    const int base = cursor[n] - len;   // k_scatter left cursor[n] at segment end

    for (int chunk = 0; chunk < len; chunk += UF) {
        const int m = len - chunk;      // team-uniform
        int src[UF];
        float2 ewv[UF];
        unsigned int y2[UF];
        unsigned short y1[UF];
        // P1: indices + edge weights (broadcast loads), all issued together
#pragma unroll
        for (int j = 0; j < UF; ++j) {
            if (j < m) {
                src[j] = srcS[base + chunk + j];
                ewv[j] = ewS[base + chunk + j];
            }
        }
        __builtin_amdgcn_sched_barrier(0);
        // P2: Y-row gathers — UF outstanding VMEM ops, pinned before compute
#pragma unroll
        for (int j = 0; j < UF; ++j) {
            if (j < m) {
                if constexpr (VC == 2)
                    y2[j] = *(const unsigned int*)(Yb + (size_t)src[j] * NOUT + c0);
                else
                    y1[j] = Yb[(size_t)src[j] * NOUT + c0];
            }
        }
        __builtin_amdgcn_sched_barrier(0);
        // P3: compute
#pragma unroll
        for (int j = 0; j < UF; ++j) {
            if (j < m) {
                if constexpr (VC == 2) {
                    float ya = b2f((unsigned short)(y2[j] & 0xffff));
                    float yb = b2f((unsigned short)(y2[j] >> 16));
                    acc[0] += fmaxf(ya + ewv[j].x * e0[0] + ewv[j].y * e1[0] + bcv[0], 0.f);
                    acc[1] += fmaxf(yb + ewv[j].x * e0[1] + ewv[j].y * e1[1] + bcv[1], 0.f);
                } else {
                    float ya = b2f(y1[j]);
                    acc[0] += fmaxf(ya + ewv[j].x * e0[0] + ewv[j].y * e1[0] + bcv[0], 0.f);
                }
            }
        }
    }

    const float inv = 1.f / (float)(len > 1 ? len : 1);
    if constexpr (VC == 2) {
        unsigned int o = (unsigned int)f2bu(acc[0] * inv)
                       | ((unsigned int)f2bu(acc[1] * inv) << 16);
        *(unsigned int*)(meanb + (size_t)n * NOUT + c0) = o;
    } else {
        meanb[(size_t)n * NOUT + c0] = f2bu(acc[0] * inv);
    }
}

// ---------------------------------------------------------------------------
// pet from bf16 xb: 16 lanes/edge, 8 bf16 per lane, shuffle reduce
// ---------------------------------------------------------------------------
__global__ __launch_bounds__(256)
void k_pet(const unsigned short* __restrict__ xb, const int* __restrict__ ei,
           const float* __restrict__ ew, const float* __restrict__ etW,
           const float* __restrict__ etb, float* __restrict__ out, int E)
{
    const int lane = threadIdx.x & 63;
    const long wg = ((long)blockIdx.x * blockDim.x + threadIdx.x) >> 6;
    const long e = wg * 4 + (lane >> 4);
    const int l16 = lane & 15;
    if (e >= E) return;
    const int s = ei[e], d = ei[E + e];
    uint4 av = ((const uint4*)(xb + (size_t)s * 128))[l16];
    uint4 bv = ((const uint4*)(xb + (size_t)d * 128))[l16];
    bf16x8 a = __builtin_bit_cast(bf16x8, av);
    bf16x8 b = __builtin_bit_cast(bf16x8, bv);
    float4 w0 = ((const float4*)etW)[l16 * 2];
    float4 w1 = ((const float4*)etW)[l16 * 2 + 1];
    float acc = fabsf((float)a[0] - (float)b[0]) * w0.x
              + fabsf((float)a[1] - (float)b[1]) * w0.y
              + fabsf((float)a[2] - (float)b[2]) * w0.z
              + fabsf((float)a[3] - (float)b[3]) * w0.w
              + fabsf((float)a[4] - (float)b[4]) * w1.x
              + fabsf((float)a[5] - (float)b[5]) * w1.y
              + fabsf((float)a[6] - (float)b[6]) * w1.z
              + fabsf((float)a[7] - (float)b[7]) * w1.w;
    acc += __shfl_xor(acc, 8);
    acc += __shfl_xor(acc, 4);
    acc += __shfl_xor(acc, 2);
    acc += __shfl_xor(acc, 1);
    if (l16 == 0)
        out[e] = acc + ew[2 * e] * etW[128] + ew[2 * e + 1] * etW[129] + etb[0];
}

// ---------------------------------------------------------------------------
extern "C" void kernel_launch(void* const* d_in, const int* in_sizes, int n_in,
                              void* d_out, int out_size, void* d_ws, size_t ws_size,
                              hipStream_t stream) {
    const float* x   = (const float*)d_in[0];
    const int*   ei  = (const int*)d_in[1];
    const float* ew  = (const float*)d_in[2];
    const float* Wc1 = (const float*)d_in[3];
    const float* bc1 = (const float*)d_in[4];
    const float* W1  = (const float*)d_in[5];
    const float* b1  = (const float*)d_in[6];
    const float* Wc2 = (const float*)d_in[7];
    const float* bc2 = (const float*)d_in[8];
    const float* W2  = (const float*)d_in[9];
    const float* b2  = (const float*)d_in[10];
    const float* Wc3 = (const float*)d_in[11];
    const float* bc3 = (const float*)d_in[12];
    const float* W3  = (const float*)d_in[13];
    const float* b3  = (const float*)d_in[14];
    const float* Wc4 = (const float*)d_in[15];
    const float* bc4 = (const float*)d_in[16];
    const float* W4  = (const float*)d_in[17];
    const float* b4  = (const float*)d_in[18];
    const float* etW = (const float*)d_in[19];
    const float* etb = (const float*)d_in[20];

    float* out   = (float*)d_out;
    float* recon = out;                              // N x 128
    float* mu    = out + (size_t)NN * 128;           // N x 64
    float* lv    = mu + (size_t)NN * 64;             // N x 64
    float* pet   = lv + (size_t)NN * 64;             // E x 1

    char* wsp = (char*)d_ws;
    unsigned short* xb  = (unsigned short*)(wsp);              // 12.8 MB
    unsigned short* Yb  = (unsigned short*)(wsp + 12800000);   // 12.8 MB (scratch Y)
    unsigned short* ab  = (unsigned short*)(wsp + 25600000);   // 12.8 MB (scratch mean)
    unsigned short* h1b = (unsigned short*)(wsp + 38400000);   // 12.8 MB
    unsigned short* zb  = (unsigned short*)(wsp + 51200000);   // 6.4 MB
    unsigned short* db  = (unsigned short*)(wsp + 57600000);   // 12.8 MB
    int* deg            = (int*)(wsp + 70400000);              // 0.2 MB
    int* cursor         = (int*)(wsp + 70600000);              // 0.2 MB
    int* srcS           = (int*)(wsp + 70800000);              // 3.2 MB
    float2* ewS         = (float2*)(wsp + 74000000);           // 6.4 MB
    int* part           = (int*)(wsp + 80400000);              // 1 KB

    const int E = NE, NV = NN;

    // ---- precompute: degree, hierarchical scan, dst-sorted (srcS, ewS), bf16 x
    hipMemsetAsync(deg, 0, NV * sizeof(int), stream);
    k_deg<<<(E + 255) / 256, 256, 0, stream>>>(ei, deg, E);
    k_scan1<<<256, 256, 0, stream>>>(deg, part, NV);
    k_scan2<<<1, 256, 0, stream>>>(part);
    k_scan3<<<256, 256, 0, stream>>>(deg, part, cursor, NV);
    k_scatter<<<(E + 255) / 256, 256, 0, stream>>>(ei, ew, cursor, srcS, ewS, E);
    k_cvt<<<(800000 + 255) / 256, 256, 0, stream>>>(x, xb, 800000);

    // ---- conv1: Y1 = xb@Wc1 ; mean ; h1 = relu(mean@W1+b1)
    k_dense<128, 128, 0><<<391, 256, 0, stream>>>(xb, Wc1, nullptr,
                                                  nullptr, nullptr, Yb, NV);
    k_agg<128><<<12500, 256, 0, stream>>>(Yb, srcS, ewS, Wc1 + 128 * 128, bc1,
                                          cursor, deg, ab, NV);
    k_dense<128, 128, 1><<<391, 256, 0, stream>>>(ab, W1, b1,
                                                  nullptr, nullptr, h1b, NV);

    // ---- conv2: Y2 = h1@Wc2 ; mean ; (mu, logvar, z) = relu(mean@W2+b2)
    k_dense<128, 128, 0><<<391, 256, 0, stream>>>(h1b, Wc2, nullptr,
                                                  nullptr, nullptr, Yb, NV);
    k_agg<128><<<12500, 256, 0, stream>>>(Yb, srcS, ewS, Wc2 + 128 * 128, bc2,
                                          cursor, deg, ab, NV);
    k_dense<128, 128, 2><<<391, 256, 0, stream>>>(ab, W2, b2,
                                                  mu, lv, zb, NV);

    // ---- pet (bf16 xb)
    k_pet<<<50000, 256, 0, stream>>>(xb, ei, ew, etW, etb, pet, E);

    // ---- conv3: Y3 = zb@Wc3 ; mean ; d = relu(mean@W3+b3)
    k_dense<64, 64, 0><<<391, 256, 0, stream>>>(zb, Wc3, nullptr,
                                                nullptr, nullptr, Yb, NV);
    k_agg<64><<<12500, 256, 0, stream>>>(Yb, srcS, ewS, Wc3 + 64 * 64, bc3,
                                         cursor, deg, ab, NV);
    k_dense<64, 128, 1><<<391, 256, 0, stream>>>(ab, W3, b3,
                                                 nullptr, nullptr, db, NV);

    // ---- conv4: Y4 = db@Wc4 ; mean ; recon = tanh(mean@W4+b4)
    k_dense<128, 128, 0><<<391, 256, 0, stream>>>(db, Wc4, nullptr,
                                                  nullptr, nullptr, Yb, NV);
    k_agg<128><<<12500, 256, 0, stream>>>(Yb, srcS, ewS, Wc4 + 128 * 128, bc4,
                                          cursor, deg, ab, NV);
    k_dense<128, 128, 3><<<391, 256, 0, stream>>>(ab, W4, b4,
                                                  recon, nullptr, nullptr, NV);
}

// Round 11
// 390.343 us; speedup vs baseline: 1.3903x; 1.3903x over previous
//
#include <hip/hip_runtime.h>
#include <hip/hip_bf16.h>

#define NN 50000
#define NE 800000

typedef __bf16 bf16x8 __attribute__((ext_vector_type(8)));
typedef float f32x4 __attribute__((ext_vector_type(4)));

__device__ __forceinline__ unsigned short f2bu(float f) {
    return __builtin_bit_cast(unsigned short, (__bf16)f);
}
__device__ __forceinline__ float b2f(unsigned short u) {
    return (float)__builtin_bit_cast(__bf16, u);
}

// ---------------------------------------------------------------------------
// f32 -> bf16 convert (x -> xb), 8 elements per thread
// ---------------------------------------------------------------------------
__global__ void k_cvt(const float* __restrict__ x, unsigned short* __restrict__ xb, int n8) {
    int i = blockIdx.x * blockDim.x + threadIdx.x;
    if (i >= n8) return;
    float4 a = ((const float4*)x)[i * 2];
    float4 b = ((const float4*)x)[i * 2 + 1];
    bf16x8 v;
    v[0] = (__bf16)a.x; v[1] = (__bf16)a.y; v[2] = (__bf16)a.z; v[3] = (__bf16)a.w;
    v[4] = (__bf16)b.x; v[5] = (__bf16)b.y; v[6] = (__bf16)b.z; v[7] = (__bf16)b.w;
    ((uint4*)xb)[i] = __builtin_bit_cast(uint4, v);
}

// ---------------------------------------------------------------------------
// in-degree histogram over dst = ei[E..2E)
// ---------------------------------------------------------------------------
__global__ void k_deg(const int* __restrict__ ei, int* __restrict__ deg, int E) {
    int e = blockIdx.x * blockDim.x + threadIdx.x;
    if (e < E) atomicAdd(&deg[ei[E + e]], 1);
}

// ---------------------------------------------------------------------------
// Hierarchical exclusive scan of deg[0..n) -> cursor, 256 blocks.
// ---------------------------------------------------------------------------
__global__ __launch_bounds__(256)
void k_scan1(const int* __restrict__ deg, int* __restrict__ part, int n) {
    const int b = blockIdx.x, t = threadIdx.x;
    const int chunk = (n + gridDim.x - 1) / gridDim.x;
    const int lo = b * chunk;
    const int cnt = min(chunk, n - lo);
    int v = (t < cnt) ? deg[lo + t] : 0;
    v += __shfl_xor(v, 1); v += __shfl_xor(v, 2); v += __shfl_xor(v, 4);
    v += __shfl_xor(v, 8); v += __shfl_xor(v, 16); v += __shfl_xor(v, 32);
    __shared__ int red[4];
    if ((t & 63) == 0) red[t >> 6] = v;
    __syncthreads();
    if (t == 0) part[b] = red[0] + red[1] + red[2] + red[3];
}

__global__ __launch_bounds__(256)
void k_scan2(int* __restrict__ part) {
    __shared__ int tmp[256];
    const int t = threadIdx.x;
    const int v = part[t];
    tmp[t] = v;
    __syncthreads();
    int val = v;
    for (int off = 1; off < 256; off <<= 1) {
        int y = (t >= off) ? tmp[t - off] : 0;
        __syncthreads();
        val += y;
        tmp[t] = val;
        __syncthreads();
    }
    part[t] = val - v;   // exclusive
}

__global__ __launch_bounds__(256)
void k_scan3(const int* __restrict__ deg, const int* __restrict__ part,
             int* __restrict__ cursor, int n) {
    __shared__ int tmp[256];
    const int b = blockIdx.x, t = threadIdx.x;
    const int chunk = (n + gridDim.x - 1) / gridDim.x;
    const int lo = b * chunk;
    const int cnt = min(chunk, n - lo);
    const int v = (t < cnt) ? deg[lo + t] : 0;
    tmp[t] = v;
    __syncthreads();
    int val = v;
    for (int off = 1; off < 256; off <<= 1) {
        int y = (t >= off) ? tmp[t - off] : 0;
        __syncthreads();
        val += y;
        tmp[t] = val;
        __syncthreads();
    }
    if (t < cnt) cursor[lo + t] = part[b] + val - v;   // exclusive + block offset
}

// ---------------------------------------------------------------------------
// scatter edges into dst-sorted order using cursor (post: cursor[n]=segment end)
// ---------------------------------------------------------------------------
__global__ void k_scatter(const int* __restrict__ ei, const float* __restrict__ ew,
                          int* __restrict__ cursor, int* __restrict__ srcS,
                          float2* __restrict__ ewS, int E) {
    int e = blockIdx.x * blockDim.x + threadIdx.x;
    if (e >= E) return;
    int d = ei[E + e];
    int s = atomicAdd(&cursor[d], 1);
    srcS[s] = ei[e];
    ewS[s] = ((const float2*)ew)[e];
}

// ---------------------------------------------------------------------------
// Dense MFMA GEMM, bf16 input rows, W/bias f32 -> registers.
// Tile 128 x NOUT, 4 waves (2x2), A fragment-major in LDS (520-pad + swizzle).
// MOUT: 0 = plain bf16 store; 1 = relu->bf16; 2 = relu->mu f32 + z bf16 /
//       logvar f32; 3 = tanh->f32
// ---------------------------------------------------------------------------
template<int KP, int NOUT, int MOUT>
__global__ __launch_bounds__(256, 2)
void k_dense(const unsigned short* __restrict__ Xb, const float* __restrict__ W,
             const float* __restrict__ bias, float* __restrict__ o0,
             float* __restrict__ o1, unsigned short* __restrict__ bo, int M)
{
    constexpr int BLOCK_M = 128;
    constexpr int CH = KP / 8;
    constexpr int KSTEPS = KP / 32;
    constexpr int FM = 4;
    constexpr int FN = NOUT / 32;
    constexpr int BLK = 520;

    __shared__ unsigned short Alds[8 * KSTEPS * BLK];

    const int tid = threadIdx.x;
    const int lane = tid & 63;
    const int w = tid >> 6;
    const int lrow = lane & 15;
    const int lkg = lane >> 4;
    const int wrow0 = (w >> 1) * 64;
    const int cb0 = (w & 1) * (NOUT / 2);

    bf16x8 bfr[KSTEPS][FN];
    float eb[FN];
#pragma unroll
    for (int nf = 0; nf < FN; ++nf) {
        int col = cb0 + nf * 16 + lrow;
#pragma unroll
        for (int ks = 0; ks < KSTEPS; ++ks)
#pragma unroll
            for (int j = 0; j < 8; ++j) {
                int k = ks * 32 + lkg * 8 + j;
                bfr[ks][nf][j] = (__bf16)W[k * NOUT + col];
            }
        if constexpr (MOUT != 0) eb[nf] = bias[col];
        else eb[nf] = 0.f;
    }

    const int ntiles = (M + BLOCK_M - 1) / BLOCK_M;
    for (int tile = blockIdx.x; tile < ntiles; tile += gridDim.x) {
        const int base = tile * BLOCK_M;
        __syncthreads();
        for (int t = tid; t < BLOCK_M * CH; t += 256) {
            int row = t / CH;
            int c = t % CH;
            int r = base + row;
            uint4 val = make_uint4(0, 0, 0, 0);
            if (r < M) val = *((const uint4*)(Xb + (size_t)r * KP) + c);
            int mb = row >> 4, lr = row & 15, ks = c >> 2, q = c & 3;
            int unit = (q * 16 + lr) ^ (q << 1);
            *(uint4*)&Alds[(mb * KSTEPS + ks) * BLK + unit * 8] = val;
        }
        __syncthreads();

        f32x4 acc[FM][FN];
#pragma unroll
        for (int mf = 0; mf < FM; ++mf)
#pragma unroll
            for (int nf = 0; nf < FN; ++nf)
                acc[mf][nf] = 0;

        const int runit = lane ^ (lkg << 1);
#pragma unroll
        for (int ks = 0; ks < KSTEPS; ++ks) {
            bf16x8 afr[FM];
#pragma unroll
            for (int mf = 0; mf < FM; ++mf) {
                int mb = (wrow0 >> 4) + mf;
                afr[mf] = *(const bf16x8*)&Alds[(mb * KSTEPS + ks) * BLK + runit * 8];
            }
#pragma unroll
            for (int mf = 0; mf < FM; ++mf)
#pragma unroll
                for (int nf = 0; nf < FN; ++nf)
                    acc[mf][nf] = __builtin_amdgcn_mfma_f32_16x16x32_bf16(
                        afr[mf], bfr[ks][nf], acc[mf][nf], 0, 0, 0);
        }

#pragma unroll
        for (int mf = 0; mf < FM; ++mf) {
#pragma unroll
            for (int reg = 0; reg < 4; ++reg) {
                int row = wrow0 + mf * 16 + lkg * 4 + reg;
                int r = base + row;
                if (r < M) {
#pragma unroll
                    for (int nf = 0; nf < FN; ++nf) {
                        int col = cb0 + nf * 16 + lrow;
                        float tv = acc[mf][nf][reg] + eb[nf];
                        if constexpr (MOUT == 0) {
                            bo[(size_t)r * NOUT + col] = f2bu(tv);
                        } else if constexpr (MOUT == 1) {
                            bo[(size_t)r * NOUT + col] = f2bu(fmaxf(tv, 0.f));
                        } else if constexpr (MOUT == 2) {
                            float v = fmaxf(tv, 0.f);
                            if (col < 64) {
                                o0[(size_t)r * 64 + col] = v;        // mu
                                bo[(size_t)r * 64 + col] = f2bu(v);  // z
                            } else {
                                o1[(size_t)r * 64 + (col - 64)] = v; // logvar
                            }
                        } else {
                            o0[(size_t)r * NOUT + col] = tanhf(tv);
                        }
                    }
                }
            }
        }
    }
}

// ---------------------------------------------------------------------------
// Per-node segment gather-reduce, 16(8)-lanes-per-node geometry:
//   mean[n] = (1/max(deg,1)) * sum_{e in seg(n)} relu(Y[srcS[e]] + ew@er + bc)
// Lane loads 8 bf16 (uint4, 16B) of its node's current edge row -> one
// wave-VMEM instruction serves NPW nodes (4 for NOUT=128, 8 for NOUT=64),
// giving NPW independent dependency chains per wave. Full chunks of 4 edges
// are UNGUARDED (named scalars, no masks) so hipcc batches the loads;
// short serial tail handles len%4. No sched_barriers (R10 lesson).
// ---------------------------------------------------------------------------
template<int NOUT>
__global__ __launch_bounds__(256)
void k_agg(const unsigned short* __restrict__ Yb, const int* __restrict__ srcS,
           const float2* __restrict__ ewS, const float* __restrict__ er,
           const float* __restrict__ bc, const int* __restrict__ cursor,
           const int* __restrict__ deg, unsigned short* __restrict__ meanb, int NV)
{
    constexpr int LPN = NOUT / 8;     // lanes per node (16 or 8)
    constexpr int NPB = 256 / LPN;    // nodes per block (16 or 32)
    const int tid = threadIdx.x;
    const int lg = tid % LPN;         // col-group within node
    const int slot = tid / LPN;
    const int n = blockIdx.x * NPB + slot;
    if (n >= NV) return;
    const int c0 = lg * 8;

    float e0[8], e1[8], bcv[8], acc[8];
#pragma unroll
    for (int v = 0; v < 8; ++v) {
        e0[v] = er[c0 + v];
        e1[v] = er[NOUT + c0 + v];
        bcv[v] = bc[c0 + v];
        acc[v] = 0.f;
    }

    const int len = deg[n];
    const int base = cursor[n] - len;   // k_scatter left cursor[n] at segment end

    auto accum = [&](uint4 yv, float2 w) {
        bf16x8 yb = __builtin_bit_cast(bf16x8, yv);
#pragma unroll
        for (int v = 0; v < 8; ++v)
            acc[v] += fmaxf((float)yb[v] + w.x * e0[v] + w.y * e1[v] + bcv[v], 0.f);
    };

    const int nfull = len >> 2;
    int i = base;
    for (int c = 0; c < nfull; ++c, i += 4) {
        // unguarded 4-wide batch: independent loads, no masks
        int s0 = srcS[i], s1 = srcS[i + 1], s2 = srcS[i + 2], s3 = srcS[i + 3];
        float2 w0 = ewS[i], w1 = ewS[i + 1], w2 = ewS[i + 2], w3 = ewS[i + 3];
        uint4 y0 = *(const uint4*)(Yb + (size_t)s0 * NOUT + c0);
        uint4 y1 = *(const uint4*)(Yb + (size_t)s1 * NOUT + c0);
        uint4 y2 = *(const uint4*)(Yb + (size_t)s2 * NOUT + c0);
        uint4 y3 = *(const uint4*)(Yb + (size_t)s3 * NOUT + c0);
        accum(y0, w0);
        accum(y1, w1);
        accum(y2, w2);
        accum(y3, w3);
    }
    for (; i < base + len; ++i) {       // tail (<=3 edges)
        int s0 = srcS[i];
        float2 w0 = ewS[i];
        uint4 y0 = *(const uint4*)(Yb + (size_t)s0 * NOUT + c0);
        accum(y0, w0);
    }

    const float inv = 1.f / (float)(len > 1 ? len : 1);
    bf16x8 ov;
#pragma unroll
    for (int v = 0; v < 8; ++v) ov[v] = (__bf16)(acc[v] * inv);
    *(uint4*)(meanb + (size_t)n * NOUT + c0) = __builtin_bit_cast(uint4, ov);
}

// ---------------------------------------------------------------------------
// pet from bf16 xb: 16 lanes/edge, 8 bf16 per lane, shuffle reduce
// ---------------------------------------------------------------------------
__global__ __launch_bounds__(256)
void k_pet(const unsigned short* __restrict__ xb, const int* __restrict__ ei,
           const float* __restrict__ ew, const float* __restrict__ etW,
           const float* __restrict__ etb, float* __restrict__ out, int E)
{
    const int lane = threadIdx.x & 63;
    const long wg = ((long)blockIdx.x * blockDim.x + threadIdx.x) >> 6;
    const long e = wg * 4 + (lane >> 4);
    const int l16 = lane & 15;
    if (e >= E) return;
    const int s = ei[e], d = ei[E + e];
    uint4 av = ((const uint4*)(xb + (size_t)s * 128))[l16];
    uint4 bv = ((const uint4*)(xb + (size_t)d * 128))[l16];
    bf16x8 a = __builtin_bit_cast(bf16x8, av);
    bf16x8 b = __builtin_bit_cast(bf16x8, bv);
    float4 w0 = ((const float4*)etW)[l16 * 2];
    float4 w1 = ((const float4*)etW)[l16 * 2 + 1];
    float acc = fabsf((float)a[0] - (float)b[0]) * w0.x
              + fabsf((float)a[1] - (float)b[1]) * w0.y
              + fabsf((float)a[2] - (float)b[2]) * w0.z
              + fabsf((float)a[3] - (float)b[3]) * w0.w
              + fabsf((float)a[4] - (float)b[4]) * w1.x
              + fabsf((float)a[5] - (float)b[5]) * w1.y
              + fabsf((float)a[6] - (float)b[6]) * w1.z
              + fabsf((float)a[7] - (float)b[7]) * w1.w;
    acc += __shfl_xor(acc, 8);
    acc += __shfl_xor(acc, 4);
    acc += __shfl_xor(acc, 2);
    acc += __shfl_xor(acc, 1);
    if (l16 == 0)
        out[e] = acc + ew[2 * e] * etW[128] + ew[2 * e + 1] * etW[129] + etb[0];
}

// ---------------------------------------------------------------------------
extern "C" void kernel_launch(void* const* d_in, const int* in_sizes, int n_in,
                              void* d_out, int out_size, void* d_ws, size_t ws_size,
                              hipStream_t stream) {
    const float* x   = (const float*)d_in[0];
    const int*   ei  = (const int*)d_in[1];
    const float* ew  = (const float*)d_in[2];
    const float* Wc1 = (const float*)d_in[3];
    const float* bc1 = (const float*)d_in[4];
    const float* W1  = (const float*)d_in[5];
    const float* b1  = (const float*)d_in[6];
    const float* Wc2 = (const float*)d_in[7];
    const float* bc2 = (const float*)d_in[8];
    const float* W2  = (const float*)d_in[9];
    const float* b2  = (const float*)d_in[10];
    const float* Wc3 = (const float*)d_in[11];
    const float* bc3 = (const float*)d_in[12];
    const float* W3  = (const float*)d_in[13];
    const float* b3  = (const float*)d_in[14];
    const float* Wc4 = (const float*)d_in[15];
    const float* bc4 = (const float*)d_in[16];
    const float* W4  = (const float*)d_in[17];
    const float* b4  = (const float*)d_in[18];
    const float* etW = (const float*)d_in[19];
    const float* etb = (const float*)d_in[20];

    float* out   = (float*)d_out;
    float* recon = out;                              // N x 128
    float* mu    = out + (size_t)NN * 128;           // N x 64
    float* lv    = mu + (size_t)NN * 64;             // N x 64
    float* pet   = lv + (size_t)NN * 64;             // E x 1

    char* wsp = (char*)d_ws;
    unsigned short* xb  = (unsigned short*)(wsp);              // 12.8 MB
    unsigned short* Yb  = (unsigned short*)(wsp + 12800000);   // 12.8 MB (scratch Y)
    unsigned short* ab  = (unsigned short*)(wsp + 25600000);   // 12.8 MB (scratch mean)
    unsigned short* h1b = (unsigned short*)(wsp + 38400000);   // 12.8 MB
    unsigned short* zb  = (unsigned short*)(wsp + 51200000);   // 6.4 MB
    unsigned short* db  = (unsigned short*)(wsp + 57600000);   // 12.8 MB
    int* deg            = (int*)(wsp + 70400000);              // 0.2 MB
    int* cursor         = (int*)(wsp + 70600000);              // 0.2 MB
    int* srcS           = (int*)(wsp + 70800000);              // 3.2 MB
    float2* ewS         = (float2*)(wsp + 74000000);           // 6.4 MB
    int* part           = (int*)(wsp + 80400000);              // 1 KB

    const int E = NE, NV = NN;

    // ---- precompute: degree, hierarchical scan, dst-sorted (srcS, ewS), bf16 x
    hipMemsetAsync(deg, 0, NV * sizeof(int), stream);
    k_deg<<<(E + 255) / 256, 256, 0, stream>>>(ei, deg, E);
    k_scan1<<<256, 256, 0, stream>>>(deg, part, NV);
    k_scan2<<<1, 256, 0, stream>>>(part);
    k_scan3<<<256, 256, 0, stream>>>(deg, part, cursor, NV);
    k_scatter<<<(E + 255) / 256, 256, 0, stream>>>(ei, ew, cursor, srcS, ewS, E);
    k_cvt<<<(800000 + 255) / 256, 256, 0, stream>>>(x, xb, 800000);

    // ---- conv1: Y1 = xb@Wc1 ; mean ; h1 = relu(mean@W1+b1)
    k_dense<128, 128, 0><<<391, 256, 0, stream>>>(xb, Wc1, nullptr,
                                                  nullptr, nullptr, Yb, NV);
    k_agg<128><<<(NN + 15) / 16, 256, 0, stream>>>(Yb, srcS, ewS, Wc1 + 128 * 128, bc1,
                                                   cursor, deg, ab, NV);
    k_dense<128, 128, 1><<<391, 256, 0, stream>>>(ab, W1, b1,
                                                  nullptr, nullptr, h1b, NV);

    // ---- conv2: Y2 = h1@Wc2 ; mean ; (mu, logvar, z) = relu(mean@W2+b2)
    k_dense<128, 128, 0><<<391, 256, 0, stream>>>(h1b, Wc2, nullptr,
                                                  nullptr, nullptr, Yb, NV);
    k_agg<128><<<(NN + 15) / 16, 256, 0, stream>>>(Yb, srcS, ewS, Wc2 + 128 * 128, bc2,
                                                   cursor, deg, ab, NV);
    k_dense<128, 128, 2><<<391, 256, 0, stream>>>(ab, W2, b2,
                                                  mu, lv, zb, NV);

    // ---- pet (bf16 xb)
    k_pet<<<50000, 256, 0, stream>>>(xb, ei, ew, etW, etb, pet, E);

    // ---- conv3: Y3 = zb@Wc3 ; mean ; d = relu(mean@W3+b3)
    k_dense<64, 64, 0><<<391, 256, 0, stream>>>(zb, Wc3, nullptr,
                                                nullptr, nullptr, Yb, NV);
    k_agg<64><<<(NN + 31) / 32, 256, 0, stream>>>(Yb, srcS, ewS, Wc3 + 64 * 64, bc3,
                                                  cursor, deg, ab, NV);
    k_dense<64, 128, 1><<<391, 256, 0, stream>>>(ab, W3, b3,
                                                 nullptr, nullptr, db, NV);

    // ---- conv4: Y4 = db@Wc4 ; mean ; recon = tanh(mean@W4+b4)
    k_dense<128, 128, 0><<<391, 256, 0, stream>>>(db, Wc4, nullptr,
                                                  nullptr, nullptr, Yb, NV);
    k_agg<128><<<(NN + 15) / 16, 256, 0, stream>>>(Yb, srcS, ewS, Wc4 + 128 * 128, bc4,
                                                   cursor, deg, ab, NV);
    k_dense<128, 128, 3><<<391, 256, 0, stream>>>(ab, W4, b4,
                                                  recon, nullptr, nullptr, NV);
}

// Round 12
// 377.433 us; speedup vs baseline: 1.4379x; 1.0342x over previous
//
#include <hip/hip_runtime.h>
#include <hip/hip_bf16.h>

#define NN 50000
#define NE 800000

typedef __bf16 bf16x8 __attribute__((ext_vector_type(8)));
typedef float f32x4 __attribute__((ext_vector_type(4)));

__device__ __forceinline__ unsigned short f2bu(float f) {
    return __builtin_bit_cast(unsigned short, (__bf16)f);
}
__device__ __forceinline__ float b2f(unsigned short u) {
    return (float)__builtin_bit_cast(__bf16, u);
}

// ---------------------------------------------------------------------------
// f32 -> bf16 convert (x -> xb), 8 elements per thread
// ---------------------------------------------------------------------------
__global__ void k_cvt(const float* __restrict__ x, unsigned short* __restrict__ xb, int n8) {
    int i = blockIdx.x * blockDim.x + threadIdx.x;
    if (i >= n8) return;
    float4 a = ((const float4*)x)[i * 2];
    float4 b = ((const float4*)x)[i * 2 + 1];
    bf16x8 v;
    v[0] = (__bf16)a.x; v[1] = (__bf16)a.y; v[2] = (__bf16)a.z; v[3] = (__bf16)a.w;
    v[4] = (__bf16)b.x; v[5] = (__bf16)b.y; v[6] = (__bf16)b.z; v[7] = (__bf16)b.w;
    ((uint4*)xb)[i] = __builtin_bit_cast(uint4, v);
}

// ---------------------------------------------------------------------------
// in-degree histogram over dst = ei[E..2E)
// ---------------------------------------------------------------------------
__global__ void k_deg(const int* __restrict__ ei, int* __restrict__ deg, int E) {
    int e = blockIdx.x * blockDim.x + threadIdx.x;
    if (e < E) atomicAdd(&deg[ei[E + e]], 1);
}

// ---------------------------------------------------------------------------
// Hierarchical exclusive scan of deg[0..n) -> cursor, 256 blocks.
// ---------------------------------------------------------------------------
__global__ __launch_bounds__(256)
void k_scan1(const int* __restrict__ deg, int* __restrict__ part, int n) {
    const int b = blockIdx.x, t = threadIdx.x;
    const int chunk = (n + gridDim.x - 1) / gridDim.x;
    const int lo = b * chunk;
    const int cnt = min(chunk, n - lo);
    int v = (t < cnt) ? deg[lo + t] : 0;
    v += __shfl_xor(v, 1); v += __shfl_xor(v, 2); v += __shfl_xor(v, 4);
    v += __shfl_xor(v, 8); v += __shfl_xor(v, 16); v += __shfl_xor(v, 32);
    __shared__ int red[4];
    if ((t & 63) == 0) red[t >> 6] = v;
    __syncthreads();
    if (t == 0) part[b] = red[0] + red[1] + red[2] + red[3];
}

__global__ __launch_bounds__(256)
void k_scan2(int* __restrict__ part) {
    __shared__ int tmp[256];
    const int t = threadIdx.x;
    const int v = part[t];
    tmp[t] = v;
    __syncthreads();
    int val = v;
    for (int off = 1; off < 256; off <<= 1) {
        int y = (t >= off) ? tmp[t - off] : 0;
        __syncthreads();
        val += y;
        tmp[t] = val;
        __syncthreads();
    }
    part[t] = val - v;   // exclusive
}

__global__ __launch_bounds__(256)
void k_scan3(const int* __restrict__ deg, const int* __restrict__ part,
             int* __restrict__ cursor, int n) {
    __shared__ int tmp[256];
    const int b = blockIdx.x, t = threadIdx.x;
    const int chunk = (n + gridDim.x - 1) / gridDim.x;
    const int lo = b * chunk;
    const int cnt = min(chunk, n - lo);
    const int v = (t < cnt) ? deg[lo + t] : 0;
    tmp[t] = v;
    __syncthreads();
    int val = v;
    for (int off = 1; off < 256; off <<= 1) {
        int y = (t >= off) ? tmp[t - off] : 0;
        __syncthreads();
        val += y;
        tmp[t] = val;
        __syncthreads();
    }
    if (t < cnt) cursor[lo + t] = part[b] + val - v;   // exclusive + block offset
}

// ---------------------------------------------------------------------------
// scatter edges into dst-sorted order (post: cursor[n]=segment end).
// Packed payload: ONE 8B record per edge {src, ew0_bf16 | ew1_bf16<<16}
// (was srcS 4B + ewS 8B in two arrays -> 8x write-amplified across XCDs).
// ---------------------------------------------------------------------------
__global__ void k_scatter(const int* __restrict__ ei, const float* __restrict__ ew,
                          int* __restrict__ cursor, int2* __restrict__ edgeS, int E) {
    int e = blockIdx.x * blockDim.x + threadIdx.x;
    if (e >= E) return;
    int d = ei[E + e];
    int s = atomicAdd(&cursor[d], 1);
    float2 w = ((const float2*)ew)[e];
    int packed = (int)((unsigned int)f2bu(w.x) | ((unsigned int)f2bu(w.y) << 16));
    edgeS[s] = make_int2(ei[e], packed);
}

// ---------------------------------------------------------------------------
// Dense MFMA GEMM, bf16 input rows, W/bias f32 -> registers.
// Tile 128 x NOUT, 4 waves (2x2), A fragment-major in LDS (520-pad + swizzle).
// MOUT: 0 = plain bf16 store; 1 = relu->bf16; 2 = relu->mu f32 + z bf16 /
//       logvar f32; 3 = tanh->f32
// ---------------------------------------------------------------------------
template<int KP, int NOUT, int MOUT>
__global__ __launch_bounds__(256, 2)
void k_dense(const unsigned short* __restrict__ Xb, const float* __restrict__ W,
             const float* __restrict__ bias, float* __restrict__ o0,
             float* __restrict__ o1, unsigned short* __restrict__ bo, int M)
{
    constexpr int BLOCK_M = 128;
    constexpr int CH = KP / 8;
    constexpr int KSTEPS = KP / 32;
    constexpr int FM = 4;
    constexpr int FN = NOUT / 32;
    constexpr int BLK = 520;

    __shared__ unsigned short Alds[8 * KSTEPS * BLK];

    const int tid = threadIdx.x;
    const int lane = tid & 63;
    const int w = tid >> 6;
    const int lrow = lane & 15;
    const int lkg = lane >> 4;
    const int wrow0 = (w >> 1) * 64;
    const int cb0 = (w & 1) * (NOUT / 2);

    bf16x8 bfr[KSTEPS][FN];
    float eb[FN];
#pragma unroll
    for (int nf = 0; nf < FN; ++nf) {
        int col = cb0 + nf * 16 + lrow;
#pragma unroll
        for (int ks = 0; ks < KSTEPS; ++ks)
#pragma unroll
            for (int j = 0; j < 8; ++j) {
                int k = ks * 32 + lkg * 8 + j;
                bfr[ks][nf][j] = (__bf16)W[k * NOUT + col];
            }
        if constexpr (MOUT != 0) eb[nf] = bias[col];
        else eb[nf] = 0.f;
    }

    const int ntiles = (M + BLOCK_M - 1) / BLOCK_M;
    for (int tile = blockIdx.x; tile < ntiles; tile += gridDim.x) {
        const int base = tile * BLOCK_M;
        __syncthreads();
        for (int t = tid; t < BLOCK_M * CH; t += 256) {
            int row = t / CH;
            int c = t % CH;
            int r = base + row;
            uint4 val = make_uint4(0, 0, 0, 0);
            if (r < M) val = *((const uint4*)(Xb + (size_t)r * KP) + c);
            int mb = row >> 4, lr = row & 15, ks = c >> 2, q = c & 3;
            int unit = (q * 16 + lr) ^ (q << 1);
            *(uint4*)&Alds[(mb * KSTEPS + ks) * BLK + unit * 8] = val;
        }
        __syncthreads();

        f32x4 acc[FM][FN];
#pragma unroll
        for (int mf = 0; mf < FM; ++mf)
#pragma unroll
            for (int nf = 0; nf < FN; ++nf)
                acc[mf][nf] = 0;

        const int runit = lane ^ (lkg << 1);
#pragma unroll
        for (int ks = 0; ks < KSTEPS; ++ks) {
            bf16x8 afr[FM];
#pragma unroll
            for (int mf = 0; mf < FM; ++mf) {
                int mb = (wrow0 >> 4) + mf;
                afr[mf] = *(const bf16x8*)&Alds[(mb * KSTEPS + ks) * BLK + runit * 8];
            }
#pragma unroll
            for (int mf = 0; mf < FM; ++mf)
#pragma unroll
                for (int nf = 0; nf < FN; ++nf)
                    acc[mf][nf] = __builtin_amdgcn_mfma_f32_16x16x32_bf16(
                        afr[mf], bfr[ks][nf], acc[mf][nf], 0, 0, 0);
        }

#pragma unroll
        for (int mf = 0; mf < FM; ++mf) {
#pragma unroll
            for (int reg = 0; reg < 4; ++reg) {
                int row = wrow0 + mf * 16 + lkg * 4 + reg;
                int r = base + row;
                if (r < M) {
#pragma unroll
                    for (int nf = 0; nf < FN; ++nf) {
                        int col = cb0 + nf * 16 + lrow;
                        float tv = acc[mf][nf][reg] + eb[nf];
                        if constexpr (MOUT == 0) {
                            bo[(size_t)r * NOUT + col] = f2bu(tv);
                        } else if constexpr (MOUT == 1) {
                            bo[(size_t)r * NOUT + col] = f2bu(fmaxf(tv, 0.f));
                        } else if constexpr (MOUT == 2) {
                            float v = fmaxf(tv, 0.f);
                            if (col < 64) {
                                o0[(size_t)r * 64 + col] = v;        // mu
                                bo[(size_t)r * 64 + col] = f2bu(v);  // z
                            } else {
                                o1[(size_t)r * 64 + (col - 64)] = v; // logvar
                            }
                        } else {
                            o0[(size_t)r * NOUT + col] = tanhf(tv);
                        }
                    }
                }
            }
        }
    }
}

// ---------------------------------------------------------------------------
// Per-node segment gather-reduce, 16(8)-lanes-per-node geometry, packed
// edge records:
//   mean[n] = (1/max(deg,1)) * sum_{e in seg(n)} relu(Y[src_e] + ew_e@er + bc)
// Lane loads 8 bf16 (uint4, 16B) of its node's current edge row -> one
// wave-VMEM instruction serves 4 (NOUT=128) / 8 (NOUT=64) nodes, giving that
// many independent dep chains per wave. Full chunks of 4 edges unguarded.
// ---------------------------------------------------------------------------
template<int NOUT>
__global__ __launch_bounds__(256)
void k_agg(const unsigned short* __restrict__ Yb, const int2* __restrict__ edgeS,
           const float* __restrict__ er, const float* __restrict__ bc,
           const int* __restrict__ cursor, const int* __restrict__ deg,
           unsigned short* __restrict__ meanb, int NV)
{
    constexpr int LPN = NOUT / 8;     // lanes per node (16 or 8)
    constexpr int NPB = 256 / LPN;    // nodes per block (16 or 32)
    const int tid = threadIdx.x;
    const int lg = tid % LPN;         // col-group within node
    const int slot = tid / LPN;
    const int n = blockIdx.x * NPB + slot;
    if (n >= NV) return;
    const int c0 = lg * 8;

    float e0[8], e1[8], bcv[8], acc[8];
#pragma unroll
    for (int v = 0; v < 8; ++v) {
        e0[v] = er[c0 + v];
        e1[v] = er[NOUT + c0 + v];
        bcv[v] = bc[c0 + v];
        acc[v] = 0.f;
    }

    const int len = deg[n];
    const int base = cursor[n] - len;   // k_scatter left cursor[n] at segment end

    auto accum = [&](uint4 yv, int packed) {
        bf16x8 yb = __builtin_bit_cast(bf16x8, yv);
        float wx = b2f((unsigned short)(packed & 0xffff));
        float wy = b2f((unsigned short)((unsigned int)packed >> 16));
#pragma unroll
        for (int v = 0; v < 8; ++v)
            acc[v] += fmaxf((float)yb[v] + wx * e0[v] + wy * e1[v] + bcv[v], 0.f);
    };

    const int nfull = len >> 2;
    int i = base;
    for (int c = 0; c < nfull; ++c, i += 4) {
        // unguarded 4-wide batch: independent loads, no masks
        int2 p0 = edgeS[i], p1 = edgeS[i + 1], p2 = edgeS[i + 2], p3 = edgeS[i + 3];
        uint4 y0 = *(const uint4*)(Yb + (size_t)p0.x * NOUT + c0);
        uint4 y1 = *(const uint4*)(Yb + (size_t)p1.x * NOUT + c0);
        uint4 y2 = *(const uint4*)(Yb + (size_t)p2.x * NOUT + c0);
        uint4 y3 = *(const uint4*)(Yb + (size_t)p3.x * NOUT + c0);
        accum(y0, p0.y);
        accum(y1, p1.y);
        accum(y2, p2.y);
        accum(y3, p3.y);
    }
    for (; i < base + len; ++i) {       // tail (<=3 edges)
        int2 p0 = edgeS[i];
        uint4 y0 = *(const uint4*)(Yb + (size_t)p0.x * NOUT + c0);
        accum(y0, p0.y);
    }

    const float inv = 1.f / (float)(len > 1 ? len : 1);
    bf16x8 ov;
#pragma unroll
    for (int v = 0; v < 8; ++v) ov[v] = (__bf16)(acc[v] * inv);
    *(uint4*)(meanb + (size_t)n * NOUT + c0) = __builtin_bit_cast(uint4, ov);
}

// ---------------------------------------------------------------------------
// pet from bf16 xb: 16 lanes/edge, 8 bf16 per lane, shuffle reduce
// ---------------------------------------------------------------------------
__global__ __launch_bounds__(256)
void k_pet(const unsigned short* __restrict__ xb, const int* __restrict__ ei,
           const float* __restrict__ ew, const float* __restrict__ etW,
           const float* __restrict__ etb, float* __restrict__ out, int E)
{
    const int lane = threadIdx.x & 63;
    const long wg = ((long)blockIdx.x * blockDim.x + threadIdx.x) >> 6;
    const long e = wg * 4 + (lane >> 4);
    const int l16 = lane & 15;
    if (e >= E) return;
    const int s = ei[e], d = ei[E + e];
    uint4 av = ((const uint4*)(xb + (size_t)s * 128))[l16];
    uint4 bv = ((const uint4*)(xb + (size_t)d * 128))[l16];
    bf16x8 a = __builtin_bit_cast(bf16x8, av);
    bf16x8 b = __builtin_bit_cast(bf16x8, bv);
    float4 w0 = ((const float4*)etW)[l16 * 2];
    float4 w1 = ((const float4*)etW)[l16 * 2 + 1];
    float acc = fabsf((float)a[0] - (float)b[0]) * w0.x
              + fabsf((float)a[1] - (float)b[1]) * w0.y
              + fabsf((float)a[2] - (float)b[2]) * w0.z
              + fabsf((float)a[3] - (float)b[3]) * w0.w
              + fabsf((float)a[4] - (float)b[4]) * w1.x
              + fabsf((float)a[5] - (float)b[5]) * w1.y
              + fabsf((float)a[6] - (float)b[6]) * w1.z
              + fabsf((float)a[7] - (float)b[7]) * w1.w;
    acc += __shfl_xor(acc, 8);
    acc += __shfl_xor(acc, 4);
    acc += __shfl_xor(acc, 2);
    acc += __shfl_xor(acc, 1);
    if (l16 == 0)
        out[e] = acc + ew[2 * e] * etW[128] + ew[2 * e + 1] * etW[129] + etb[0];
}

// ---------------------------------------------------------------------------
extern "C" void kernel_launch(void* const* d_in, const int* in_sizes, int n_in,
                              void* d_out, int out_size, void* d_ws, size_t ws_size,
                              hipStream_t stream) {
    const float* x   = (const float*)d_in[0];
    const int*   ei  = (const int*)d_in[1];
    const float* ew  = (const float*)d_in[2];
    const float* Wc1 = (const float*)d_in[3];
    const float* bc1 = (const float*)d_in[4];
    const float* W1  = (const float*)d_in[5];
    const float* b1  = (const float*)d_in[6];
    const float* Wc2 = (const float*)d_in[7];
    const float* bc2 = (const float*)d_in[8];
    const float* W2  = (const float*)d_in[9];
    const float* b2  = (const float*)d_in[10];
    const float* Wc3 = (const float*)d_in[11];
    const float* bc3 = (const float*)d_in[12];
    const float* W3  = (const float*)d_in[13];
    const float* b3  = (const float*)d_in[14];
    const float* Wc4 = (const float*)d_in[15];
    const float* bc4 = (const float*)d_in[16];
    const float* W4  = (const float*)d_in[17];
    const float* b4  = (const float*)d_in[18];
    const float* etW = (const float*)d_in[19];
    const float* etb = (const float*)d_in[20];

    float* out   = (float*)d_out;
    float* recon = out;                              // N x 128
    float* mu    = out + (size_t)NN * 128;           // N x 64
    float* lv    = mu + (size_t)NN * 64;             // N x 64
    float* pet   = lv + (size_t)NN * 64;             // E x 1

    char* wsp = (char*)d_ws;
    unsigned short* xb  = (unsigned short*)(wsp);              // 12.8 MB
    unsigned short* Yb  = (unsigned short*)(wsp + 12800000);   // 12.8 MB (scratch Y)
    unsigned short* ab  = (unsigned short*)(wsp + 25600000);   // 12.8 MB (scratch mean)
    unsigned short* h1b = (unsigned short*)(wsp + 38400000);   // 12.8 MB
    unsigned short* zb  = (unsigned short*)(wsp + 51200000);   // 6.4 MB
    unsigned short* db  = (unsigned short*)(wsp + 57600000);   // 12.8 MB
    int* deg            = (int*)(wsp + 70400000);              // 0.2 MB
    int* cursor         = (int*)(wsp + 70600000);              // 0.2 MB
    int2* edgeS         = (int2*)(wsp + 70800000);             // 6.4 MB
    int* part           = (int*)(wsp + 77200000);              // 1 KB

    const int E = NE, NV = NN;

    // ---- precompute: degree, hierarchical scan, dst-sorted packed edges, bf16 x
    hipMemsetAsync(deg, 0, NV * sizeof(int), stream);
    k_deg<<<(E + 255) / 256, 256, 0, stream>>>(ei, deg, E);
    k_scan1<<<256, 256, 0, stream>>>(deg, part, NV);
    k_scan2<<<1, 256, 0, stream>>>(part);
    k_scan3<<<256, 256, 0, stream>>>(deg, part, cursor, NV);
    k_scatter<<<(E + 255) / 256, 256, 0, stream>>>(ei, ew, cursor, edgeS, E);
    k_cvt<<<(800000 + 255) / 256, 256, 0, stream>>>(x, xb, 800000);

    // ---- conv1: Y1 = xb@Wc1 ; mean ; h1 = relu(mean@W1+b1)
    k_dense<128, 128, 0><<<391, 256, 0, stream>>>(xb, Wc1, nullptr,
                                                  nullptr, nullptr, Yb, NV);
    k_agg<128><<<(NN + 15) / 16, 256, 0, stream>>>(Yb, edgeS, Wc1 + 128 * 128, bc1,
                                                   cursor, deg, ab, NV);
    k_dense<128, 128, 1><<<391, 256, 0, stream>>>(ab, W1, b1,
                                                  nullptr, nullptr, h1b, NV);

    // ---- conv2: Y2 = h1@Wc2 ; mean ; (mu, logvar, z) = relu(mean@W2+b2)
    k_dense<128, 128, 0><<<391, 256, 0, stream>>>(h1b, Wc2, nullptr,
                                                  nullptr, nullptr, Yb, NV);
    k_agg<128><<<(NN + 15) / 16, 256, 0, stream>>>(Yb, edgeS, Wc2 + 128 * 128, bc2,
                                                   cursor, deg, ab, NV);
    k_dense<128, 128, 2><<<391, 256, 0, stream>>>(ab, W2, b2,
                                                  mu, lv, zb, NV);

    // ---- pet (bf16 xb)
    k_pet<<<50000, 256, 0, stream>>>(xb, ei, ew, etW, etb, pet, E);

    // ---- conv3: Y3 = zb@Wc3 ; mean ; d = relu(mean@W3+b3)
    k_dense<64, 64, 0><<<391, 256, 0, stream>>>(zb, Wc3, nullptr,
                                                nullptr, nullptr, Yb, NV);
    k_agg<64><<<(NN + 31) / 32, 256, 0, stream>>>(Yb, edgeS, Wc3 + 64 * 64, bc3,
                                                  cursor, deg, ab, NV);
    k_dense<64, 128, 1><<<391, 256, 0, stream>>>(ab, W3, b3,
                                                 nullptr, nullptr, db, NV);

    // ---- conv4: Y4 = db@Wc4 ; mean ; recon = tanh(mean@W4+b4)
    k_dense<128, 128, 0><<<391, 256, 0, stream>>>(db, Wc4, nullptr,
                                                  nullptr, nullptr, Yb, NV);
    k_agg<128><<<(NN + 15) / 16, 256, 0, stream>>>(Yb, edgeS, Wc4 + 128 * 128, bc4,
                                                   cursor, deg, ab, NV);
    k_dense<128, 128, 3><<<391, 256, 0, stream>>>(ab, W4, b4,
                                                  recon, nullptr, nullptr, NV);
}